// Round 1
// baseline (869.511 us; speedup 1.0000x reference)
//
#include <hip/hip_runtime.h>
#include <hip/hip_bf16.h>
#include <math.h>

#define N_NODES 200000
#define MEM_DIM 256
#define MSG_DIM 256
#define BATCH 2048
#define NSLOTS (2*BATCH)      // 4096 update slots: 2*i = src of event i, 2*i+1 = dst
#define IN1 515               // 2*MEM_DIM + 3
#define K1PAD 528             // IN1 padded to multiple of 16
#define G3 768                // 3*MEM_DIM

// ---- workspace layout (float offsets) ----
#define OFF_X      0
#define SZ_X       (BATCH*K1PAD)
#define OFF_W1P    (OFF_X + SZ_X)
#define SZ_W1P     (MSG_DIM*K1PAD)
#define OFF_HMID   (OFF_W1P + SZ_W1P)
#define SZ_HMID    (BATCH*MSG_DIM)
#define OFF_MSG    (OFF_HMID + SZ_HMID)
#define SZ_MSG     (BATCH*MSG_DIM)
#define OFF_PREGI  (OFF_MSG + SZ_MSG)
#define SZ_PREGI   (BATCH*G3)
#define OFF_WHHT   (OFF_PREGI + SZ_PREGI)
#define SZ_WHHT    (G3*MEM_DIM)
#define OFF_INTS   (OFF_WHHT + SZ_WHHT)
// int region: nodes[4096], next[4096], head_list[4096], head_count[1]

// Pad W1 (256 x 515) to (256 x 528) with zeros so the GEMM K-loop is a
// multiple of 16 and float4 loads stay in-bounds.
__global__ void pack_w1(const float* __restrict__ W1, float* __restrict__ W1p) {
    int i = blockIdx.x * 256 + threadIdx.x;
    if (i >= MSG_DIM * K1PAD) return;
    int n = i / K1PAD, k = i - n * K1PAD;
    W1p[i] = (k < IN1) ? W1[n * IN1 + k] : 0.f;
}

// X[ev] = [memory[src], memory[dst], edge_feat, zeros-pad]  (2048 x 528)
__global__ void build_x(const int* __restrict__ src, const int* __restrict__ dst,
                        const float* __restrict__ ef, const float* __restrict__ memory,
                        float* __restrict__ X) {
    int ev = blockIdx.x;
    int s = src[ev], d = dst[ev];
    const float* sm = memory + (long)s * MEM_DIM;
    const float* dm = memory + (long)d * MEM_DIM;
    float* x = X + (long)ev * K1PAD;
    for (int i = threadIdx.x; i < K1PAD; i += 256) {
        float v;
        if (i < 256)      v = sm[i];
        else if (i < 512) v = dm[i - 256];
        else if (i < 515) v = ef[ev * 3 + (i - 512)];
        else              v = 0.f;
        x[i] = v;
    }
}

// whhT[k*768 + j] = whh[j*256 + k]  (coalesced chain-kernel matvec reads)
__global__ void transpose_whh(const float* __restrict__ whh, float* __restrict__ whhT) {
    __shared__ float tile[32][33];
    int jb = blockIdx.x * 32;   // over 768
    int kb = blockIdx.y * 32;   // over 256
    int tx = threadIdx.x & 31, ty = threadIdx.x >> 5;  // 32 x 8
    #pragma unroll
    for (int r = 0; r < 32; r += 8)
        tile[ty + r][tx] = whh[(long)(jb + ty + r) * 256 + kb + tx];
    __syncthreads();
    #pragma unroll
    for (int r = 0; r < 32; r += 8)
        whhT[(long)(kb + ty + r) * G3 + jb + tx] = tile[tx][ty + r];
}

// C[M,N] = act(A[M,K] @ B[N,K]^T + bias), 64x64 block tile, 4x4 per thread.
template<bool RELU>
__global__ void gemm_bias(const float* __restrict__ A, int lda,
                          const float* __restrict__ B, int ldb,
                          const float* __restrict__ bias,
                          float* __restrict__ C, int ldc, int K) {
    __shared__ float As[16][64];
    __shared__ float Bs[16][64];
    int m0 = blockIdx.x * 64, n0 = blockIdx.y * 64;
    int tid = threadIdx.x;
    int tm = tid >> 4, tn = tid & 15;
    int lr = tid >> 2, lq = tid & 3;
    float acc[4][4] = {};
    for (int k0 = 0; k0 < K; k0 += 16) {
        float4 av = *(const float4*)&A[(long)(m0 + lr) * lda + k0 + lq * 4];
        float4 bv = *(const float4*)&B[(long)(n0 + lr) * ldb + k0 + lq * 4];
        __syncthreads();
        As[lq * 4 + 0][lr] = av.x; As[lq * 4 + 1][lr] = av.y;
        As[lq * 4 + 2][lr] = av.z; As[lq * 4 + 3][lr] = av.w;
        Bs[lq * 4 + 0][lr] = bv.x; Bs[lq * 4 + 1][lr] = bv.y;
        Bs[lq * 4 + 2][lr] = bv.z; Bs[lq * 4 + 3][lr] = bv.w;
        __syncthreads();
        #pragma unroll
        for (int kk = 0; kk < 16; ++kk) {
            float4 a = *(const float4*)&As[kk][tm * 4];
            float4 b = *(const float4*)&Bs[kk][tn * 4];
            const float* ap = (const float*)&a;
            const float* bp = (const float*)&b;
            #pragma unroll
            for (int i = 0; i < 4; ++i)
                #pragma unroll
                for (int j = 0; j < 4; ++j)
                    acc[i][j] += ap[i] * bp[j];
        }
    }
    #pragma unroll
    for (int i = 0; i < 4; ++i) {
        int row = m0 + tm * 4 + i;
        float4 o;
        float* op = (float*)&o;
        #pragma unroll
        for (int j = 0; j < 4; ++j) {
            float v = acc[i][j] + bias[n0 + tn * 4 + j];
            if (RELU) v = fmaxf(v, 0.f);
            op[j] = v;
        }
        *(float4*)&C[(long)row * ldc + n0 + tn * 4] = o;
    }
}

// Per slot u: node id, next slot touching same node (-1 if none), and append
// chain heads (no earlier slot with same node) to head_list.
__global__ void build_links(const int* __restrict__ src, const int* __restrict__ dst,
                            int* __restrict__ nodes, int* __restrict__ nxt,
                            int* __restrict__ head_list, int* __restrict__ head_count) {
    __shared__ int sn[NSLOTS];
    for (int i = threadIdx.x; i < NSLOTS; i += 256) {
        int ev = i >> 1;
        sn[i] = (i & 1) ? dst[ev] : src[ev];
    }
    __syncthreads();
    int u = blockIdx.x * 256 + threadIdx.x;   // grid = 16 blocks, u < 4096 always
    int me = sn[u];
    nodes[u] = me;
    int nx = -1;
    for (int w = u + 1; w < NSLOTS; ++w)
        if (sn[w] == me) { nx = w; break; }
    nxt[u] = nx;
    bool head = true;
    for (int w = u - 1; w >= 0; --w)
        if (sn[w] == me) { head = false; break; }
    if (head) {
        int p = atomicAdd(head_count, 1);
        head_list[p] = u;
    }
}

// Bulk copy: memory -> out[0 .. N*D), last_update -> out[N*D .. N*D+N)
__global__ void copy_out(const float4* __restrict__ mem4, const float4* __restrict__ lu4,
                         float4* __restrict__ out4) {
    const long NM4 = (long)N_NODES * MEM_DIM / 4;  // 12,800,000
    const long NT4 = NM4 + N_NODES / 4;            // 12,850,000
    for (long i = (long)blockIdx.x * 256 + threadIdx.x; i < NT4; i += (long)gridDim.x * 256)
        out4[i] = (i < NM4) ? mem4[i] : lu4[i - NM4];
}

// 8 independent per-node GRU chains per block, 256 threads.
// Per step: gh = whh@h + bhh as an 8x768 mini-matvec vs whhT (coalesced),
// then gates per thread t (t owns output element t of each chain's h).
#define CPB 8
__global__ void chain_kernel(const int* __restrict__ nodes, const int* __restrict__ nxt,
                             const int* __restrict__ head_list, const int* __restrict__ head_count,
                             const float* __restrict__ memory,
                             const float* __restrict__ pregi,
                             const float* __restrict__ whhT,
                             const float* __restrict__ bhh,
                             const float* __restrict__ ts,
                             float* __restrict__ out_mem, float* __restrict__ out_lu) {
    __shared__ __align__(16) float hs[CPB][MEM_DIM];
    int t = threadIdx.x;
    int hc = *head_count;
    int base = blockIdx.x * CPB;
    int u[CPB], v[CPB];
    float tl[CPB];
    bool any = false;
    #pragma unroll
    for (int c = 0; c < CPB; ++c) {
        int idx = base + c;
        if (idx < hc) { u[c] = head_list[idx]; v[c] = nodes[u[c]]; any = true; }
        else          { u[c] = -1; v[c] = -1; }
        tl[c] = 0.f;
    }
    if (!any) return;
    #pragma unroll
    for (int c = 0; c < CPB; ++c)
        hs[c][t] = (v[c] >= 0) ? memory[(long)v[c] * MEM_DIM + t] : 0.f;
    float bh0 = bhh[t], bh1 = bhh[256 + t], bh2 = bhh[512 + t];

    while (true) {
        bool act = false;
        #pragma unroll
        for (int c = 0; c < CPB; ++c) act = act || (u[c] >= 0);
        if (!act) break;
        __syncthreads();   // hs stable for all threads
        float a0[CPB], a1[CPB], a2[CPB];
        #pragma unroll
        for (int c = 0; c < CPB; ++c) { a0[c] = bh0; a1[c] = bh1; a2[c] = bh2; }
        for (int k = 0; k < MEM_DIM; k += 4) {
            float4 hv[CPB];
            #pragma unroll
            for (int c = 0; c < CPB; ++c) hv[c] = *(const float4*)&hs[c][k];
            #pragma unroll
            for (int q = 0; q < 4; ++q) {
                float w0 = whhT[(long)(k + q) * G3 + t];
                float w1 = whhT[(long)(k + q) * G3 + 256 + t];
                float w2 = whhT[(long)(k + q) * G3 + 512 + t];
                #pragma unroll
                for (int c = 0; c < CPB; ++c) {
                    float hk = ((const float*)&hv[c])[q];
                    a0[c] += hk * w0; a1[c] += hk * w1; a2[c] += hk * w2;
                }
            }
        }
        float hn[CPB];
        #pragma unroll
        for (int c = 0; c < CPB; ++c) {
            if (u[c] < 0) { hn[c] = 0.f; continue; }
            int ev = u[c] >> 1;
            float gi0 = pregi[(long)ev * G3 + t];
            float gi1 = pregi[(long)ev * G3 + 256 + t];
            float gi2 = pregi[(long)ev * G3 + 512 + t];
            float r = 1.f / (1.f + expf(-(gi0 + a0[c])));
            float z = 1.f / (1.f + expf(-(gi1 + a1[c])));
            float n = tanhf(gi2 + r * a2[c]);
            hn[c] = (1.f - z) * n + z * hs[c][t];
            tl[c] = ts[ev];
        }
        __syncthreads();   // all matvec reads of hs done
        #pragma unroll
        for (int c = 0; c < CPB; ++c)
            if (u[c] >= 0) { hs[c][t] = hn[c]; u[c] = nxt[u[c]]; }
    }
    #pragma unroll
    for (int c = 0; c < CPB; ++c) {
        if (v[c] < 0) continue;
        out_mem[(long)v[c] * MEM_DIM + t] = hs[c][t];
        if (t == 0) out_lu[v[c]] = tl[c];
    }
}

extern "C" void kernel_launch(void* const* d_in, const int* in_sizes, int n_in,
                              void* d_out, int out_size, void* d_ws, size_t ws_size,
                              hipStream_t stream) {
    (void)in_sizes; (void)n_in; (void)out_size; (void)ws_size;
    const int*   src    = (const int*)d_in[0];
    const int*   dst    = (const int*)d_in[1];
    const float* ef     = (const float*)d_in[2];
    const float* ts     = (const float*)d_in[3];
    const float* memory = (const float*)d_in[4];
    const float* lastup = (const float*)d_in[5];
    const float* W1     = (const float*)d_in[6];
    const float* b1     = (const float*)d_in[7];
    const float* W2     = (const float*)d_in[8];
    const float* b2     = (const float*)d_in[9];
    const float* wih    = (const float*)d_in[10];
    const float* whh    = (const float*)d_in[11];
    const float* bih    = (const float*)d_in[12];
    const float* bhh    = (const float*)d_in[13];

    float* ws    = (float*)d_ws;
    float* X     = ws + OFF_X;
    float* W1p   = ws + OFF_W1P;
    float* Hmid  = ws + OFF_HMID;
    float* msg   = ws + OFF_MSG;
    float* pregi = ws + OFF_PREGI;
    float* whhT  = ws + OFF_WHHT;
    int*   ints  = (int*)(ws + OFF_INTS);
    int* nodes = ints;
    int* nxt   = ints + NSLOTS;
    int* hlist = ints + 2 * NSLOTS;
    int* hcnt  = ints + 3 * NSLOTS;

    hipMemsetAsync(hcnt, 0, sizeof(int), stream);
    pack_w1<<<(SZ_W1P + 255) / 256, 256, 0, stream>>>(W1, W1p);
    build_x<<<BATCH, 256, 0, stream>>>(src, dst, ef, memory, X);
    transpose_whh<<<dim3(G3 / 32, MEM_DIM / 32), 256, 0, stream>>>(whh, whhT);
    // Hmid = relu(X @ W1p^T + b1)
    gemm_bias<true><<<dim3(BATCH / 64, MSG_DIM / 64), 256, 0, stream>>>(
        X, K1PAD, W1p, K1PAD, b1, Hmid, MSG_DIM, K1PAD);
    // msg = Hmid @ W2^T + b2
    gemm_bias<false><<<dim3(BATCH / 64, MSG_DIM / 64), 256, 0, stream>>>(
        Hmid, MSG_DIM, W2, MSG_DIM, b2, msg, MSG_DIM, MSG_DIM);
    // pregi = msg @ wih^T + bih   (shared by src and dst slot of each event)
    gemm_bias<false><<<dim3(BATCH / 64, G3 / 64), 256, 0, stream>>>(
        msg, MSG_DIM, wih, MSG_DIM, bih, pregi, G3, MSG_DIM);
    build_links<<<16, 256, 0, stream>>>(src, dst, nodes, nxt, hlist, hcnt);
    copy_out<<<2048, 256, 0, stream>>>((const float4*)memory, (const float4*)lastup,
                                       (float4*)d_out);
    chain_kernel<<<NSLOTS / CPB, 256, 0, stream>>>(
        nodes, nxt, hlist, hcnt, memory, pregi, whhT, bhh, ts,
        (float*)d_out, (float*)d_out + (long)N_NODES * MEM_DIM);
}

// Round 3
// 550.010 us; speedup vs baseline: 1.5809x; 1.5809x over previous
//
#include <hip/hip_runtime.h>
#include <hip/hip_bf16.h>
#include <math.h>
#include <limits.h>

#define N_NODES 200000
#define MEM_DIM 256
#define MSG_DIM 256
#define BATCH 2048
#define NSLOTS (2*BATCH)      // 4096 update slots: 2*i = src of event i, 2*i+1 = dst
#define IN1 515               // 2*MEM_DIM + 3
#define K1PAD 528             // IN1 padded to multiple of 16
#define G3 768                // 3*MEM_DIM

// ---- workspace layout (float offsets) ----
#define OFF_X      0
#define SZ_X       (BATCH*K1PAD)
#define OFF_W1P    (OFF_X + SZ_X)
#define SZ_W1P     (MSG_DIM*K1PAD)
#define OFF_HMID   (OFF_W1P + SZ_W1P)
#define SZ_HMID    (BATCH*MSG_DIM)
#define OFF_MSG    (OFF_HMID + SZ_HMID)
#define SZ_MSG     (BATCH*MSG_DIM)
#define OFF_PREGI  (OFF_MSG + SZ_MSG)
#define SZ_PREGI   (BATCH*G3)
#define OFF_WHHT   (OFF_PREGI + SZ_PREGI)
#define SZ_WHHT    (G3*MEM_DIM)
#define OFF_INTS   (OFF_WHHT + SZ_WHHT)
// int region: nodes[4096], next[4096], head_list[4096], head_count[1]

// Pad W1 (256 x 515) to (256 x 528) with zeros so the GEMM K-loop is a
// multiple of 16 and float4 loads stay in-bounds.
__global__ void pack_w1(const float* __restrict__ W1, float* __restrict__ W1p) {
    int i = blockIdx.x * 256 + threadIdx.x;
    if (i >= MSG_DIM * K1PAD) return;
    int n = i / K1PAD, k = i - n * K1PAD;
    W1p[i] = (k < IN1) ? W1[n * IN1 + k] : 0.f;
}

// X[ev] = [memory[src], memory[dst], edge_feat, zeros-pad]  (2048 x 528)
__global__ void build_x(const int* __restrict__ src, const int* __restrict__ dst,
                        const float* __restrict__ ef, const float* __restrict__ memory,
                        float* __restrict__ X) {
    int ev = blockIdx.x;
    int s = src[ev], d = dst[ev];
    const float* sm = memory + (long)s * MEM_DIM;
    const float* dm = memory + (long)d * MEM_DIM;
    float* x = X + (long)ev * K1PAD;
    for (int i = threadIdx.x; i < K1PAD; i += 256) {
        float v;
        if (i < 256)      v = sm[i];
        else if (i < 512) v = dm[i - 256];
        else if (i < 515) v = ef[ev * 3 + (i - 512)];
        else              v = 0.f;
        x[i] = v;
    }
}

// whhT[k*768 + j] = whh[j*256 + k]  (coalesced chain-kernel matvec reads)
__global__ void transpose_whh(const float* __restrict__ whh, float* __restrict__ whhT) {
    __shared__ float tile[32][33];
    int jb = blockIdx.x * 32;   // over 768
    int kb = blockIdx.y * 32;   // over 256
    int tx = threadIdx.x & 31, ty = threadIdx.x >> 5;  // 32 x 8
    #pragma unroll
    for (int r = 0; r < 32; r += 8)
        tile[ty + r][tx] = whh[(long)(jb + ty + r) * 256 + kb + tx];
    __syncthreads();
    #pragma unroll
    for (int r = 0; r < 32; r += 8)
        whhT[(long)(kb + ty + r) * G3 + jb + tx] = tile[tx][ty + r];
}

// C[M,N] = act(A[M,K] @ B[N,K]^T + bias), 64x64 block tile, 4x4 per thread.
template<bool RELU>
__global__ void gemm_bias(const float* __restrict__ A, int lda,
                          const float* __restrict__ B, int ldb,
                          const float* __restrict__ bias,
                          float* __restrict__ C, int ldc, int K) {
    __shared__ float As[16][64];
    __shared__ float Bs[16][64];
    int m0 = blockIdx.x * 64, n0 = blockIdx.y * 64;
    int tid = threadIdx.x;
    int tm = tid >> 4, tn = tid & 15;
    int lr = tid >> 2, lq = tid & 3;
    float acc[4][4] = {};
    for (int k0 = 0; k0 < K; k0 += 16) {
        float4 av = *(const float4*)&A[(long)(m0 + lr) * lda + k0 + lq * 4];
        float4 bv = *(const float4*)&B[(long)(n0 + lr) * ldb + k0 + lq * 4];
        __syncthreads();
        As[lq * 4 + 0][lr] = av.x; As[lq * 4 + 1][lr] = av.y;
        As[lq * 4 + 2][lr] = av.z; As[lq * 4 + 3][lr] = av.w;
        Bs[lq * 4 + 0][lr] = bv.x; Bs[lq * 4 + 1][lr] = bv.y;
        Bs[lq * 4 + 2][lr] = bv.z; Bs[lq * 4 + 3][lr] = bv.w;
        __syncthreads();
        #pragma unroll
        for (int kk = 0; kk < 16; ++kk) {
            float4 a = *(const float4*)&As[kk][tm * 4];
            float4 b = *(const float4*)&Bs[kk][tn * 4];
            const float* ap = (const float*)&a;
            const float* bp = (const float*)&b;
            #pragma unroll
            for (int i = 0; i < 4; ++i)
                #pragma unroll
                for (int j = 0; j < 4; ++j)
                    acc[i][j] += ap[i] * bp[j];
        }
    }
    #pragma unroll
    for (int i = 0; i < 4; ++i) {
        int row = m0 + tm * 4 + i;
        float4 o;
        float* op = (float*)&o;
        #pragma unroll
        for (int j = 0; j < 4; ++j) {
            float v = acc[i][j] + bias[n0 + tn * 4 + j];
            if (RELU) v = fmaxf(v, 0.f);
            op[j] = v;
        }
        *(float4*)&C[(long)row * ldc + n0 + tn * 4] = o;
    }
}

// Per slot u: node id, next slot touching same node (-1 if none), and append
// chain heads (no earlier slot with same node) to head_list.
// Cooperative version: each block owns ULB slots; all 256 threads scan the
// 4096-slot node array together (16 LDS iters/thread) and reduce via LDS
// atomics. Replaces the 16-block serial-scan version (345 us -> target <10).
#define ULB 4
__global__ void build_links(const int* __restrict__ src, const int* __restrict__ dst,
                            int* __restrict__ nodes, int* __restrict__ nxt,
                            int* __restrict__ head_list, int* __restrict__ head_count) {
    __shared__ int sn[NSLOTS];
    __shared__ int smin[ULB];
    __shared__ int searly[ULB];
    for (int i = threadIdx.x; i < NSLOTS; i += 256) {
        int ev = i >> 1;
        sn[i] = (i & 1) ? dst[ev] : src[ev];
    }
    if (threadIdx.x < ULB) { smin[threadIdx.x] = INT_MAX; searly[threadIdx.x] = 0; }
    __syncthreads();
    int u0 = blockIdx.x * ULB;
    int myn[ULB];
    #pragma unroll
    for (int c = 0; c < ULB; ++c) myn[c] = sn[u0 + c];
    int lmin[ULB]; int learly[ULB];
    #pragma unroll
    for (int c = 0; c < ULB; ++c) { lmin[c] = INT_MAX; learly[c] = 0; }
    for (int w = threadIdx.x; w < NSLOTS; w += 256) {
        int nw = sn[w];
        #pragma unroll
        for (int c = 0; c < ULB; ++c) {
            if (nw == myn[c]) {
                int u = u0 + c;
                if (w > u)      lmin[c] = min(lmin[c], w);
                else if (w < u) learly[c] = 1;
            }
        }
    }
    #pragma unroll
    for (int c = 0; c < ULB; ++c) {
        if (lmin[c] != INT_MAX) atomicMin(&smin[c], lmin[c]);
        if (learly[c])          atomicOr(&searly[c], 1);
    }
    __syncthreads();
    if (threadIdx.x < ULB) {
        int u = u0 + threadIdx.x;
        nodes[u] = myn[threadIdx.x];
        int nx = smin[threadIdx.x];
        nxt[u] = (nx == INT_MAX) ? -1 : nx;
        if (!searly[threadIdx.x]) {
            int p = atomicAdd(head_count, 1);
            head_list[p] = u;
        }
    }
}

// Bulk copy: memory -> out[0 .. N*D), last_update -> out[N*D .. N*D+N)
__global__ void copy_out(const float4* __restrict__ mem4, const float4* __restrict__ lu4,
                         float4* __restrict__ out4) {
    const long NM4 = (long)N_NODES * MEM_DIM / 4;  // 12,800,000
    const long NT4 = NM4 + N_NODES / 4;            // 12,850,000
    for (long i = (long)blockIdx.x * 256 + threadIdx.x; i < NT4; i += (long)gridDim.x * 256)
        out4[i] = (i < NM4) ? mem4[i] : lu4[i - NM4];
}

// 8 independent per-node GRU chains per block, 256 threads.
// Per step: gh = whh@h + bhh as an 8x768 mini-matvec vs whhT (coalesced),
// then gates per thread t (t owns output element t of each chain's h).
#define CPB 8
__global__ void chain_kernel(const int* __restrict__ nodes, const int* __restrict__ nxt,
                             const int* __restrict__ head_list, const int* __restrict__ head_count,
                             const float* __restrict__ memory,
                             const float* __restrict__ pregi,
                             const float* __restrict__ whhT,
                             const float* __restrict__ bhh,
                             const float* __restrict__ ts,
                             float* __restrict__ out_mem, float* __restrict__ out_lu) {
    __shared__ __align__(16) float hs[CPB][MEM_DIM];
    int t = threadIdx.x;
    int hc = *head_count;
    int base = blockIdx.x * CPB;
    int u[CPB], v[CPB];
    float tl[CPB];
    bool any = false;
    #pragma unroll
    for (int c = 0; c < CPB; ++c) {
        int idx = base + c;
        if (idx < hc) { u[c] = head_list[idx]; v[c] = nodes[u[c]]; any = true; }
        else          { u[c] = -1; v[c] = -1; }
        tl[c] = 0.f;
    }
    if (!any) return;
    #pragma unroll
    for (int c = 0; c < CPB; ++c)
        hs[c][t] = (v[c] >= 0) ? memory[(long)v[c] * MEM_DIM + t] : 0.f;
    float bh0 = bhh[t], bh1 = bhh[256 + t], bh2 = bhh[512 + t];

    while (true) {
        bool act = false;
        #pragma unroll
        for (int c = 0; c < CPB; ++c) act = act || (u[c] >= 0);
        if (!act) break;
        __syncthreads();   // hs stable for all threads
        float a0[CPB], a1[CPB], a2[CPB];
        #pragma unroll
        for (int c = 0; c < CPB; ++c) { a0[c] = bh0; a1[c] = bh1; a2[c] = bh2; }
        for (int k = 0; k < MEM_DIM; k += 4) {
            float4 hv[CPB];
            #pragma unroll
            for (int c = 0; c < CPB; ++c) hv[c] = *(const float4*)&hs[c][k];
            #pragma unroll
            for (int q = 0; q < 4; ++q) {
                float w0 = whhT[(long)(k + q) * G3 + t];
                float w1 = whhT[(long)(k + q) * G3 + 256 + t];
                float w2 = whhT[(long)(k + q) * G3 + 512 + t];
                #pragma unroll
                for (int c = 0; c < CPB; ++c) {
                    float hk = ((const float*)&hv[c])[q];
                    a0[c] += hk * w0; a1[c] += hk * w1; a2[c] += hk * w2;
                }
            }
        }
        float hn[CPB];
        #pragma unroll
        for (int c = 0; c < CPB; ++c) {
            if (u[c] < 0) { hn[c] = 0.f; continue; }
            int ev = u[c] >> 1;
            float gi0 = pregi[(long)ev * G3 + t];
            float gi1 = pregi[(long)ev * G3 + 256 + t];
            float gi2 = pregi[(long)ev * G3 + 512 + t];
            float r = 1.f / (1.f + expf(-(gi0 + a0[c])));
            float z = 1.f / (1.f + expf(-(gi1 + a1[c])));
            float n = tanhf(gi2 + r * a2[c]);
            hn[c] = (1.f - z) * n + z * hs[c][t];
            tl[c] = ts[ev];
        }
        __syncthreads();   // all matvec reads of hs done
        #pragma unroll
        for (int c = 0; c < CPB; ++c)
            if (u[c] >= 0) { hs[c][t] = hn[c]; u[c] = nxt[u[c]]; }
    }
    #pragma unroll
    for (int c = 0; c < CPB; ++c) {
        if (v[c] < 0) continue;
        out_mem[(long)v[c] * MEM_DIM + t] = hs[c][t];
        if (t == 0) out_lu[v[c]] = tl[c];
    }
}

extern "C" void kernel_launch(void* const* d_in, const int* in_sizes, int n_in,
                              void* d_out, int out_size, void* d_ws, size_t ws_size,
                              hipStream_t stream) {
    (void)in_sizes; (void)n_in; (void)out_size; (void)ws_size;
    const int*   src    = (const int*)d_in[0];
    const int*   dst    = (const int*)d_in[1];
    const float* ef     = (const float*)d_in[2];
    const float* ts     = (const float*)d_in[3];
    const float* memory = (const float*)d_in[4];
    const float* lastup = (const float*)d_in[5];
    const float* W1     = (const float*)d_in[6];
    const float* b1     = (const float*)d_in[7];
    const float* W2     = (const float*)d_in[8];
    const float* b2     = (const float*)d_in[9];
    const float* wih    = (const float*)d_in[10];
    const float* whh    = (const float*)d_in[11];
    const float* bih    = (const float*)d_in[12];
    const float* bhh    = (const float*)d_in[13];

    float* ws    = (float*)d_ws;
    float* X     = ws + OFF_X;
    float* W1p   = ws + OFF_W1P;
    float* Hmid  = ws + OFF_HMID;
    float* msg   = ws + OFF_MSG;
    float* pregi = ws + OFF_PREGI;
    float* whhT  = ws + OFF_WHHT;
    int*   ints  = (int*)(ws + OFF_INTS);
    int* nodes = ints;
    int* nxt   = ints + NSLOTS;
    int* hlist = ints + 2 * NSLOTS;
    int* hcnt  = ints + 3 * NSLOTS;

    hipMemsetAsync(hcnt, 0, sizeof(int), stream);
    pack_w1<<<(SZ_W1P + 255) / 256, 256, 0, stream>>>(W1, W1p);
    build_x<<<BATCH, 256, 0, stream>>>(src, dst, ef, memory, X);
    transpose_whh<<<dim3(G3 / 32, MEM_DIM / 32), 256, 0, stream>>>(whh, whhT);
    // Hmid = relu(X @ W1p^T + b1)
    gemm_bias<true><<<dim3(BATCH / 64, MSG_DIM / 64), 256, 0, stream>>>(
        X, K1PAD, W1p, K1PAD, b1, Hmid, MSG_DIM, K1PAD);
    // msg = Hmid @ W2^T + b2
    gemm_bias<false><<<dim3(BATCH / 64, MSG_DIM / 64), 256, 0, stream>>>(
        Hmid, MSG_DIM, W2, MSG_DIM, b2, msg, MSG_DIM, MSG_DIM);
    // pregi = msg @ wih^T + bih   (shared by src and dst slot of each event)
    gemm_bias<false><<<dim3(BATCH / 64, G3 / 64), 256, 0, stream>>>(
        msg, MSG_DIM, wih, MSG_DIM, bih, pregi, G3, MSG_DIM);
    build_links<<<NSLOTS / ULB, 256, 0, stream>>>(src, dst, nodes, nxt, hlist, hcnt);
    copy_out<<<2048, 256, 0, stream>>>((const float4*)memory, (const float4*)lastup,
                                       (float4*)d_out);
    chain_kernel<<<NSLOTS / CPB, 256, 0, stream>>>(
        nodes, nxt, hlist, hcnt, memory, pregi, whhT, bhh, ts,
        (float*)d_out, (float*)d_out + (long)N_NODES * MEM_DIM);
}

// Round 5
// 534.196 us; speedup vs baseline: 1.6277x; 1.0296x over previous
//
#include <hip/hip_runtime.h>
#include <hip/hip_bf16.h>
#include <math.h>
#include <limits.h>

#define N_NODES 200000
#define MEM_DIM 256
#define MSG_DIM 256
#define BATCH 2048
#define NSLOTS (2*BATCH)      // 4096 update slots: 2*i = src of event i, 2*i+1 = dst
#define IN1 515               // 2*MEM_DIM + 3
#define K1PAD 528             // IN1 padded to multiple of 16
#define G3 768                // 3*MEM_DIM
#define NBMWORDS 6250         // ceil(200000/32) touched-node bitmap words

// ---- workspace layout (float offsets) ----
#define OFF_X      0
#define SZ_X       (BATCH*K1PAD)
#define OFF_W1P    (OFF_X + SZ_X)
#define SZ_W1P     (MSG_DIM*K1PAD)
#define OFF_HMID   (OFF_W1P + SZ_W1P)
#define SZ_HMID    (BATCH*MSG_DIM)
#define OFF_MSG    (OFF_HMID + SZ_HMID)
#define SZ_MSG     (BATCH*MSG_DIM)
#define OFF_PREGI  (OFF_MSG + SZ_MSG)
#define SZ_PREGI   (BATCH*G3)
#define OFF_WHHT   (OFF_PREGI + SZ_PREGI)
#define SZ_WHHT    (G3*MEM_DIM)
#define OFF_INTS   (OFF_WHHT + SZ_WHHT)
// int region: nodes[4096], next[4096], head_list[4096], head_count[1],
//             work_ctr[1], bitmap[6250]   (head_count..bitmap memset to 0)

// Pad W1 (256 x 515) to (256 x 528) with zeros so the GEMM K-loop is a
// multiple of 16 and float4 loads stay in-bounds.
__global__ void pack_w1(const float* __restrict__ W1, float* __restrict__ W1p) {
    int i = blockIdx.x * 256 + threadIdx.x;
    if (i >= MSG_DIM * K1PAD) return;
    int n = i / K1PAD, k = i - n * K1PAD;
    W1p[i] = (k < IN1) ? W1[n * IN1 + k] : 0.f;
}

// X[ev] = [memory[src], memory[dst], edge_feat, zeros-pad]  (2048 x 528)
__global__ void build_x(const int* __restrict__ src, const int* __restrict__ dst,
                        const float* __restrict__ ef, const float* __restrict__ memory,
                        float* __restrict__ X) {
    int ev = blockIdx.x;
    int s = src[ev], d = dst[ev];
    const float* sm = memory + (long)s * MEM_DIM;
    const float* dm = memory + (long)d * MEM_DIM;
    float* x = X + (long)ev * K1PAD;
    for (int i = threadIdx.x; i < K1PAD; i += 256) {
        float v;
        if (i < 256)      v = sm[i];
        else if (i < 512) v = dm[i - 256];
        else if (i < 515) v = ef[ev * 3 + (i - 512)];
        else              v = 0.f;
        x[i] = v;
    }
}

// whhT[k*768 + j] = whh[j*256 + k]  (coalesced chain matvec reads)
__global__ void transpose_whh(const float* __restrict__ whh, float* __restrict__ whhT) {
    __shared__ float tile[32][33];
    int jb = blockIdx.x * 32;   // over 768
    int kb = blockIdx.y * 32;   // over 256
    int tx = threadIdx.x & 31, ty = threadIdx.x >> 5;  // 32 x 8
    #pragma unroll
    for (int r = 0; r < 32; r += 8)
        tile[ty + r][tx] = whh[(long)(jb + ty + r) * 256 + kb + tx];
    __syncthreads();
    #pragma unroll
    for (int r = 0; r < 32; r += 8)
        whhT[(long)(kb + ty + r) * G3 + jb + tx] = tile[tx][ty + r];
}

// C[M,N] = act(A[M,K] @ B[N,K]^T + bias), 64x64 block tile, 4x4 per thread.
template<bool RELU>
__global__ void gemm_bias(const float* __restrict__ A, int lda,
                          const float* __restrict__ B, int ldb,
                          const float* __restrict__ bias,
                          float* __restrict__ C, int ldc, int K) {
    __shared__ float As[16][64];
    __shared__ float Bs[16][64];
    int m0 = blockIdx.x * 64, n0 = blockIdx.y * 64;
    int tid = threadIdx.x;
    int tm = tid >> 4, tn = tid & 15;
    int lr = tid >> 2, lq = tid & 3;
    float acc[4][4] = {};
    for (int k0 = 0; k0 < K; k0 += 16) {
        float4 av = *(const float4*)&A[(long)(m0 + lr) * lda + k0 + lq * 4];
        float4 bv = *(const float4*)&B[(long)(n0 + lr) * ldb + k0 + lq * 4];
        __syncthreads();
        As[lq * 4 + 0][lr] = av.x; As[lq * 4 + 1][lr] = av.y;
        As[lq * 4 + 2][lr] = av.z; As[lq * 4 + 3][lr] = av.w;
        Bs[lq * 4 + 0][lr] = bv.x; Bs[lq * 4 + 1][lr] = bv.y;
        Bs[lq * 4 + 2][lr] = bv.z; Bs[lq * 4 + 3][lr] = bv.w;
        __syncthreads();
        #pragma unroll
        for (int kk = 0; kk < 16; ++kk) {
            float4 a = *(const float4*)&As[kk][tm * 4];
            float4 b = *(const float4*)&Bs[kk][tn * 4];
            const float* ap = (const float*)&a;
            const float* bp = (const float*)&b;
            #pragma unroll
            for (int i = 0; i < 4; ++i)
                #pragma unroll
                for (int j = 0; j < 4; ++j)
                    acc[i][j] += ap[i] * bp[j];
        }
    }
    #pragma unroll
    for (int i = 0; i < 4; ++i) {
        int row = m0 + tm * 4 + i;
        float4 o;
        float* op = (float*)&o;
        #pragma unroll
        for (int j = 0; j < 4; ++j) {
            float v = acc[i][j] + bias[n0 + tn * 4 + j];
            if (RELU) v = fmaxf(v, 0.f);
            op[j] = v;
        }
        *(float4*)&C[(long)row * ldc + n0 + tn * 4] = o;
    }
}

// Per slot u: node id, next slot touching same node (-1 if none), chain heads,
// and a touched-node bitmap (copy path skips these nodes -> copy/chain are
// order-independent and can be fused/overlapped).
#define ULB 4
__global__ void build_links(const int* __restrict__ src, const int* __restrict__ dst,
                            int* __restrict__ nodes, int* __restrict__ nxt,
                            int* __restrict__ head_list, int* __restrict__ head_count,
                            unsigned int* __restrict__ bitmap) {
    __shared__ int sn[NSLOTS];
    __shared__ int smin[ULB];
    __shared__ int searly[ULB];
    for (int i = threadIdx.x; i < NSLOTS; i += 256) {
        int ev = i >> 1;
        sn[i] = (i & 1) ? dst[ev] : src[ev];
    }
    if (threadIdx.x < ULB) { smin[threadIdx.x] = INT_MAX; searly[threadIdx.x] = 0; }
    __syncthreads();
    int u0 = blockIdx.x * ULB;
    int myn[ULB];
    #pragma unroll
    for (int c = 0; c < ULB; ++c) myn[c] = sn[u0 + c];
    int lmin[ULB]; int learly[ULB];
    #pragma unroll
    for (int c = 0; c < ULB; ++c) { lmin[c] = INT_MAX; learly[c] = 0; }
    for (int w = threadIdx.x; w < NSLOTS; w += 256) {
        int nw = sn[w];
        #pragma unroll
        for (int c = 0; c < ULB; ++c) {
            if (nw == myn[c]) {
                int u = u0 + c;
                if (w > u)      lmin[c] = min(lmin[c], w);
                else if (w < u) learly[c] = 1;
            }
        }
    }
    #pragma unroll
    for (int c = 0; c < ULB; ++c) {
        if (lmin[c] != INT_MAX) atomicMin(&smin[c], lmin[c]);
        if (learly[c])          atomicOr(&searly[c], 1);
    }
    __syncthreads();
    if (threadIdx.x < ULB) {
        int u = u0 + threadIdx.x;
        int me = myn[threadIdx.x];
        nodes[u] = me;
        atomicOr(&bitmap[me >> 5], 1u << (me & 31));
        int nx = smin[threadIdx.x];
        nxt[u] = (nx == INT_MAX) ? -1 : nx;
        if (!searly[threadIdx.x]) {
            int p = atomicAdd(head_count, 1);
            head_list[p] = u;
        }
    }
}

// Fused copy + chain. Blocks 0..NCHAIN_BLKS-1 first run CPB GRU chains each
// (8x768 mini-matvec per step vs whhT), then join the work-stealing copy.
// Blocks >= NCHAIN_BLKS copy immediately (saturating HBM while chains run).
// Copy skips touched nodes (bitmap); chain writes those rows -> every d_out
// element written exactly once, no ordering required.
#define CPB 8
#define NCHAIN_BLKS (NSLOTS / CPB)   // 512
#define COPY_GRID 2048
#define COPY_CHUNK 8192L             // float4s per work-steal grab (128 KB)
__global__ void copy_chain(const int* __restrict__ nodes, const int* __restrict__ nxt,
                           const int* __restrict__ head_list, const int* __restrict__ head_count,
                           const unsigned int* __restrict__ bitmap,
                           const float* __restrict__ memory,
                           const float* __restrict__ pregi,
                           const float* __restrict__ whhT,
                           const float* __restrict__ bhh,
                           const float* __restrict__ ts,
                           const float* __restrict__ lastup,
                           float* __restrict__ out_mem, float* __restrict__ out_lu,
                           int* __restrict__ wctr) {
    __shared__ __align__(16) float hs[CPB][MEM_DIM];
    __shared__ int chunkBase;
    int t = threadIdx.x;

    if (blockIdx.x < NCHAIN_BLKS) {
        int hc = *head_count;
        int base = blockIdx.x * CPB;
        if (base < hc) {                       // block-uniform
            int u[CPB], v[CPB];
            float tl[CPB];
            #pragma unroll
            for (int c = 0; c < CPB; ++c) {
                int idx = base + c;
                if (idx < hc) { u[c] = head_list[idx]; v[c] = nodes[u[c]]; }
                else          { u[c] = -1; v[c] = -1; }
                tl[c] = 0.f;
            }
            #pragma unroll
            for (int c = 0; c < CPB; ++c)
                hs[c][t] = (v[c] >= 0) ? memory[(long)v[c] * MEM_DIM + t] : 0.f;
            float bh0 = bhh[t], bh1 = bhh[256 + t], bh2 = bhh[512 + t];

            while (true) {
                bool act = false;              // block-uniform (u[] uniform)
                #pragma unroll
                for (int c = 0; c < CPB; ++c) act = act || (u[c] >= 0);
                if (!act) break;
                __syncthreads();               // hs stable for all threads
                float a0[CPB], a1[CPB], a2[CPB];
                #pragma unroll
                for (int c = 0; c < CPB; ++c) { a0[c] = bh0; a1[c] = bh1; a2[c] = bh2; }
                for (int k = 0; k < MEM_DIM; k += 4) {
                    float4 hv[CPB];
                    #pragma unroll
                    for (int c = 0; c < CPB; ++c) hv[c] = *(const float4*)&hs[c][k];
                    #pragma unroll
                    for (int q = 0; q < 4; ++q) {
                        float w0 = whhT[(long)(k + q) * G3 + t];
                        float w1 = whhT[(long)(k + q) * G3 + 256 + t];
                        float w2 = whhT[(long)(k + q) * G3 + 512 + t];
                        #pragma unroll
                        for (int c = 0; c < CPB; ++c) {
                            float hk = ((const float*)&hv[c])[q];
                            a0[c] += hk * w0; a1[c] += hk * w1; a2[c] += hk * w2;
                        }
                    }
                }
                float hn[CPB];
                #pragma unroll
                for (int c = 0; c < CPB; ++c) {
                    if (u[c] < 0) { hn[c] = 0.f; continue; }
                    int ev = u[c] >> 1;
                    float gi0 = pregi[(long)ev * G3 + t];
                    float gi1 = pregi[(long)ev * G3 + 256 + t];
                    float gi2 = pregi[(long)ev * G3 + 512 + t];
                    float r = 1.f / (1.f + expf(-(gi0 + a0[c])));
                    float z = 1.f / (1.f + expf(-(gi1 + a1[c])));
                    float n = tanhf(gi2 + r * a2[c]);
                    hn[c] = (1.f - z) * n + z * hs[c][t];
                    tl[c] = ts[ev];
                }
                __syncthreads();               // matvec reads of hs done
                #pragma unroll
                for (int c = 0; c < CPB; ++c)
                    if (u[c] >= 0) { hs[c][t] = hn[c]; u[c] = nxt[u[c]]; }
            }
            #pragma unroll
            for (int c = 0; c < CPB; ++c) {
                if (v[c] < 0) continue;
                out_mem[(long)v[c] * MEM_DIM + t] = hs[c][t];
                if (t == 0) out_lu[v[c]] = tl[c];
            }
        }
    }

    // ---- work-stealing copy phase (all blocks) ----
    const long NM4 = (long)N_NODES * MEM_DIM / 4;  // 12,800,000
    const long NT4 = NM4 + N_NODES / 4;            // + 50,000 (lu as float4)
    const float4* mem4 = (const float4*)memory;
    const float4* lu4  = (const float4*)lastup;
    float4* out4 = (float4*)out_mem;
    while (true) {
        if (t == 0) chunkBase = atomicAdd(wctr, 1);
        __syncthreads();
        long c0 = (long)chunkBase * COPY_CHUNK;
        __syncthreads();
        if (c0 >= NT4) break;                  // block-uniform
        long cend = c0 + COPY_CHUNK; if (cend > NT4) cend = NT4;
        for (long i = c0 + t; i < cend; i += 256) {
            if (i < NM4) {
                int node = (int)(i >> 6);      // 64 float4 per node row
                if (!((bitmap[node >> 5] >> (node & 31)) & 1u))
                    out4[i] = mem4[i];
            } else {
                long j4 = i - NM4;             // lu float4 index
                float4 lv = lu4[j4];
                const float* lp = (const float*)&lv;
                int n0 = (int)(j4 * 4);
                #pragma unroll
                for (int e = 0; e < 4; ++e) {
                    int n = n0 + e;
                    if (!((bitmap[n >> 5] >> (n & 31)) & 1u))
                        out_lu[n] = lp[e];
                }
            }
        }
    }
}

extern "C" void kernel_launch(void* const* d_in, const int* in_sizes, int n_in,
                              void* d_out, int out_size, void* d_ws, size_t ws_size,
                              hipStream_t stream) {
    (void)in_sizes; (void)n_in; (void)out_size; (void)ws_size;
    const int*   src    = (const int*)d_in[0];
    const int*   dst    = (const int*)d_in[1];
    const float* ef     = (const float*)d_in[2];
    const float* ts     = (const float*)d_in[3];
    const float* memory = (const float*)d_in[4];
    const float* lastup = (const float*)d_in[5];
    const float* W1     = (const float*)d_in[6];
    const float* b1     = (const float*)d_in[7];
    const float* W2     = (const float*)d_in[8];
    const float* b2     = (const float*)d_in[9];
    const float* wih    = (const float*)d_in[10];
    const float* whh    = (const float*)d_in[11];
    const float* bih    = (const float*)d_in[12];
    const float* bhh    = (const float*)d_in[13];

    float* ws    = (float*)d_ws;
    float* X     = ws + OFF_X;
    float* W1p   = ws + OFF_W1P;
    float* Hmid  = ws + OFF_HMID;
    float* msg   = ws + OFF_MSG;
    float* pregi = ws + OFF_PREGI;
    float* whhT  = ws + OFF_WHHT;
    int*   ints  = (int*)(ws + OFF_INTS);
    int* nodes = ints;
    int* nxt   = ints + NSLOTS;
    int* hlist = ints + 2 * NSLOTS;
    int* hcnt  = ints + 3 * NSLOTS;
    int* wctr  = ints + 3 * NSLOTS + 1;
    unsigned int* bitmap = (unsigned int*)(ints + 3 * NSLOTS + 2);

    // zero head_count, work counter, and touched bitmap in one memset
    hipMemsetAsync(hcnt, 0, (2 + NBMWORDS) * sizeof(int), stream);
    pack_w1<<<(SZ_W1P + 255) / 256, 256, 0, stream>>>(W1, W1p);
    build_x<<<BATCH, 256, 0, stream>>>(src, dst, ef, memory, X);
    transpose_whh<<<dim3(G3 / 32, MEM_DIM / 32), 256, 0, stream>>>(whh, whhT);
    // Hmid = relu(X @ W1p^T + b1)
    gemm_bias<true><<<dim3(BATCH / 64, MSG_DIM / 64), 256, 0, stream>>>(
        X, K1PAD, W1p, K1PAD, b1, Hmid, MSG_DIM, K1PAD);
    // msg = Hmid @ W2^T + b2
    gemm_bias<false><<<dim3(BATCH / 64, MSG_DIM / 64), 256, 0, stream>>>(
        Hmid, MSG_DIM, W2, MSG_DIM, b2, msg, MSG_DIM, MSG_DIM);
    // pregi = msg @ wih^T + bih   (shared by src and dst slot of each event)
    gemm_bias<false><<<dim3(BATCH / 64, G3 / 64), 256, 0, stream>>>(
        msg, MSG_DIM, wih, MSG_DIM, bih, pregi, G3, MSG_DIM);
    build_links<<<NSLOTS / ULB, 256, 0, stream>>>(src, dst, nodes, nxt, hlist, hcnt, bitmap);
    copy_chain<<<COPY_GRID, 256, 0, stream>>>(
        nodes, nxt, hlist, hcnt, bitmap, memory, pregi, whhT, bhh, ts, lastup,
        (float*)d_out, (float*)d_out + (long)N_NODES * MEM_DIM, wctr);
}